// Round 1
// baseline (1629.752 us; speedup 1.0000x reference)
//
#include <hip/hip_runtime.h>

#define ENS 7
#define SDIM 30
#define ADIM 8
#define DIN 38          // SDIM + ADIM
#define HID 200
#define DOUT 31         // SDIM + RDIM
#define NHL 3           // hidden layers
#define NPAD 208        // N (out-cols) padded to 16
#define KPAD 224        // K padded to 32
#define K1PAD 64        // layer-1 K (38) padded
#define HS 232          // hA row stride in elems (bank-safe, %8==0)
#define WSTR 40         // W-chunk row stride in elems (bank-safe, %8==0)
#define MT 64           // rows per block

typedef __bf16 bf16x8 __attribute__((ext_vector_type(8)));
typedef float f32x4 __attribute__((ext_vector_type(4)));

// ws layout (ushort elems): bf16 W^T, zero-padded
#define OFF_W1 0
#define SZ_W1 (ENS * NPAD * K1PAD)            // 93184
#define OFF_WH (OFF_W1 + SZ_W1)
#define SZ_WH (NHL * ENS * NPAD * KPAD)       // 978432
#define OFF_HD (OFF_WH + SZ_WH)
#define SZ_HD (ENS * 64 * KPAD)               // 100352 (mu rows 0..31, sig rows 32..63)
#define WS_TOTAL (OFF_HD + SZ_HD)             // 1171968 ushorts = 2.34 MB

__device__ __forceinline__ unsigned short f2bf(float f) {
    unsigned u = __float_as_uint(f);
    u += 0x7fffu + ((u >> 16) & 1u);          // RNE
    return (unsigned short)(u >> 16);
}

__device__ __forceinline__ float softplusf(float x) {
    float ax = fabsf(x);
    return fmaxf(x, 0.f) + log1pf(__expf(-ax));
}

// ---- prep: fp32 weights -> bf16 W^T (padded) in ws ----
__global__ void prep_kernel(const float* __restrict__ W1, const float* __restrict__ Wh,
                            const float* __restrict__ Wmu, const float* __restrict__ Wsig,
                            unsigned short* __restrict__ ws) {
    int idx = blockIdx.x * 256 + threadIdx.x;
    if (idx >= WS_TOTAL) return;
    float v = 0.f;
    if (idx < OFF_WH) {                        // layer 1: [e][n=208][k=64]
        int r = idx;
        int e = r / (NPAD * K1PAD); r %= NPAD * K1PAD;
        int n = r / K1PAD, k = r % K1PAD;
        if (n < HID && k < DIN) v = W1[(e * DIN + k) * HID + n];
    } else if (idx < OFF_HD) {                 // hidden: [l*7+e][n=208][k=224]
        int r = idx - OFF_WH;
        int le = r / (NPAD * KPAD); r %= NPAD * KPAD;
        int n = r / KPAD, k = r % KPAD;
        if (n < HID && k < HID) v = Wh[((long)le * HID + k) * HID + n];
    } else {                                   // heads: [e][n=64][k=224]
        int r = idx - OFF_HD;
        int e = r / (64 * KPAD); r %= 64 * KPAD;
        int n = r / KPAD, k = r % KPAD;
        if (k < HID) {
            if (n < DOUT) v = Wmu[(e * HID + k) * DOUT + n];
            else if (n >= 32 && n < 32 + DOUT) v = Wsig[(e * HID + k) * DOUT + (n - 32)];
        }
    }
    ws[idx] = f2bf(v);
}

// ---- fused 5-layer ensemble MLP ----
__launch_bounds__(256, 2)
__global__ void ens_mlp_kernel(const float* __restrict__ s, const float* __restrict__ a,
                               const float* __restrict__ b1, const float* __restrict__ bh,
                               const float* __restrict__ bmu, const float* __restrict__ bsig,
                               const float* __restrict__ maxs, const float* __restrict__ mins,
                               const float* __restrict__ maxr, const float* __restrict__ minr,
                               const unsigned short* __restrict__ ws,
                               float* __restrict__ out, int N) {
    __shared__ unsigned short hA[MT * HS];          // 29696 B, activations (bf16)
    __shared__ unsigned short wB[2][NPAD * WSTR];   // 33280 B, W^T K-chunk double buffer

    const int tid = threadIdx.x;
    const int wv = tid >> 6, lane = tid & 63;
    const int quad = lane >> 4, l16 = lane & 15;
    const int bid = blockIdx.x;
    const int e = bid % ENS, n0 = (bid / ENS) * MT;

    // zero hA (pad cols must be 0)
    for (int i = tid; i < MT * HS / 8; i += 256) ((uint4*)hA)[i] = make_uint4(0, 0, 0, 0);
    __syncthreads();

    // stage x = concat(s, a) -> hA cols 0..37 (bf16)
    for (int i = tid; i < MT * DIN; i += 256) {
        int m = i / DIN, c = i % DIN;
        long g = n0 + m;
        float v = (c < SDIM) ? s[(g * ENS + e) * SDIM + c]
                             : a[(g * ENS + e) * ADIM + (c - SDIM)];
        hA[m * HS + c] = f2bf(v);
    }

    f32x4 acc[4][4];

    auto stageChunk = [&](const unsigned short* gW, int rstride, int nrows, int kc,
                          unsigned short* dst) {
        int items = nrows * 4;                 // 16B pieces: 32 k-elems = 4 x ushort8
        for (int i = tid; i < items; i += 256) {
            int n = i >> 2, j = i & 3;
            *((uint4*)(dst + n * WSTR + j * 8)) =
                *((const uint4*)(gW + n * rstride + kc + j * 8));
        }
    };

    // one layer: out[64][NT*16] = hA[64][K] @ W^T(rows=n), K-chunked, double-buffered
    auto runLayer = [&](const unsigned short* gW, int rstride, int nrows, int nsteps, int NT) {
        int nct = (NT - wv + 3) >> 2;          // col-tiles owned by this wave (ct = wv + 4j)
        for (int r = 0; r < 4; r++)
            for (int j = 0; j < 4; j++) acc[r][j] = (f32x4){0.f, 0.f, 0.f, 0.f};
        stageChunk(gW, rstride, nrows, 0, wB[0]);
        __syncthreads();
        for (int st = 0; st < nsteps; ++st) {
            if (st + 1 < nsteps) stageChunk(gW, rstride, nrows, (st + 1) * 32, wB[(st + 1) & 1]);
            const unsigned short* wb = wB[st & 1];
            const int kb = st * 32;
            bf16x8 af[4];
#pragma unroll
            for (int r = 0; r < 4; r++)
                af[r] = *((const bf16x8*)(hA + (r * 16 + l16) * HS + kb + quad * 8));
            for (int j = 0; j < nct; j++) {
                int ct = wv + 4 * j;
                bf16x8 bf_ = *((const bf16x8*)(wb + (ct * 16 + l16) * WSTR + quad * 8));
#pragma unroll
                for (int r = 0; r < 4; r++)
                    acc[r][j] = __builtin_amdgcn_mfma_f32_16x16x32_bf16(af[r], bf_, acc[r][j], 0, 0, 0);
            }
            __syncthreads();
        }
    };

    // bias + swish, write back to hA as bf16
    auto epiH = [&](const float* bias, int NT) {
        int nct = (NT - wv + 3) >> 2;
        for (int j = 0; j < nct; j++) {
            int ct = wv + 4 * j, col = ct * 16 + l16;
            float bc = (col < HID) ? bias[col] : 0.f;
#pragma unroll
            for (int r = 0; r < 4; r++)
#pragma unroll
                for (int i = 0; i < 4; i++) {
                    float v = acc[r][j][i] + bc;
                    float sw = v / (1.f + __expf(-v));   // swish
                    hA[(r * 16 + quad * 4 + i) * HS + col] = f2bf(sw);
                }
        }
    };

    // layer 1 (K=64: 2 chunks), hidden x3 (K=224: 7 chunks), heads (NT=4)
    runLayer(ws + OFF_W1 + e * NPAD * K1PAD, K1PAD, NPAD, 2, 13);
    epiH(b1 + e * HID, 13);
    for (int l = 0; l < NHL; l++) {
        runLayer(ws + OFF_WH + (l * ENS + e) * NPAD * KPAD, KPAD, NPAD, 7, 13);
        epiH(bh + (l * ENS + e) * HID, 13);
    }
    runLayer(ws + OFF_HD + e * 64 * KPAD, KPAD, 64, 7, 4);

    // head epilogue: raw mu/sig (+bias) into fp32 scratch overlaying hA
    float* scr = (float*)hA;                   // [64][64]: cols 0..31 mu, 32..63 sig
    {
        int col = wv * 16 + l16;
        float bc = 0.f;
        if (col < DOUT) bc = bmu[e * DOUT + col];
        else if (col >= 32 && col < 32 + DOUT) bc = bsig[e * DOUT + (col - 32)];
#pragma unroll
        for (int r = 0; r < 4; r++)
#pragma unroll
            for (int i = 0; i < 4; i++)
                scr[(r * 16 + quad * 4 + i) * 64 + col] = acc[r][0][i] + bc;
    }
    __syncthreads();

    const long off1 = (long)N * ENS * SDIM;    // ds_sg
    const long off2 = 2 * off1;                // r_mu
    const long off3 = off2 + (long)N * ENS;    // r_sg

    // mu outputs (no transform)
    for (int i = tid; i < MT * DOUT; i += 256) {
        int m = i / DOUT, c = i % DOUT;
        long g = n0 + m;
        float v = scr[m * 64 + c];
        if (c < SDIM) out[(g * ENS + e) * SDIM + c] = v;
        else out[off2 + g * ENS + e] = v;
    }
    // sigma outputs (clamped-softplus + exp)
    for (int i = tid; i < MT * DOUT; i += 256) {
        int m = i / DOUT, c = i % DOUT;
        long g = n0 + m;
        float v = scr[m * 64 + 32 + c];
        float mx = (c < SDIM) ? maxs[c] : maxr[0];
        float mn = (c < SDIM) ? mins[c] : minr[0];
        v = 0.5f * (mx - softplusf(mx - 2.f * v));
        v = 0.5f * (mn + softplusf(2.f * v - mn));
        v = __expf(v);
        if (c < SDIM) out[off1 + (g * ENS + e) * SDIM + c] = v;
        else out[off3 + g * ENS + e] = v;
    }
}

extern "C" void kernel_launch(void* const* d_in, const int* in_sizes, int n_in,
                              void* d_out, int out_size, void* d_ws, size_t ws_size,
                              hipStream_t stream) {
    const float* s    = (const float*)d_in[0];
    const float* a    = (const float*)d_in[1];
    const float* W1   = (const float*)d_in[2];
    const float* b1   = (const float*)d_in[3];
    const float* Wh   = (const float*)d_in[4];
    const float* bh   = (const float*)d_in[5];
    const float* Wmu  = (const float*)d_in[6];
    const float* bmu  = (const float*)d_in[7];
    const float* Wsig = (const float*)d_in[8];
    const float* bsig = (const float*)d_in[9];
    const float* maxs = (const float*)d_in[10];
    const float* mins = (const float*)d_in[11];
    const float* maxr = (const float*)d_in[12];
    const float* minr = (const float*)d_in[13];
    float* out = (float*)d_out;
    unsigned short* ws = (unsigned short*)d_ws;

    int N = in_sizes[0] / (ENS * SDIM);        // 32768

    int prepBlocks = (WS_TOTAL + 255) / 256;
    prep_kernel<<<prepBlocks, 256, 0, stream>>>(W1, Wh, Wmu, Wsig, ws);

    int mainBlocks = (N / MT) * ENS;           // 3584
    ens_mlp_kernel<<<mainBlocks, 256, 0, stream>>>(s, a, b1, bh, bmu, bsig,
                                                   maxs, mins, maxr, minr, ws, out, N);
}

// Round 2
// 528.794 us; speedup vs baseline: 3.0820x; 3.0820x over previous
//
#include <hip/hip_runtime.h>

#define ENS 7
#define SDIM 30
#define ADIM 8
#define DIN 38          // SDIM + ADIM
#define HID 200
#define DOUT 31         // SDIM + RDIM
#define NHL 3           // hidden layers
#define NPAD 208        // N (out-cols) padded to 16
#define KPAD 224        // K padded to 32
#define K1PAD 64        // layer-1 K (38) padded
#define HS 232          // hA row stride in elems (bank-safe, %8==0)
#define WSTR 40         // W-chunk row stride in elems (bank-safe, %8==0)
#define MT 64           // rows per block

typedef __bf16 bf16x8 __attribute__((ext_vector_type(8)));
typedef float f32x4 __attribute__((ext_vector_type(4)));

// ws layout (ushort elems): bf16 W^T, zero-padded
#define OFF_W1 0
#define SZ_W1 (ENS * NPAD * K1PAD)            // 93184
#define OFF_WH (OFF_W1 + SZ_W1)
#define SZ_WH (NHL * ENS * NPAD * KPAD)       // 978432
#define OFF_HD (OFF_WH + SZ_WH)
#define SZ_HD (ENS * 64 * KPAD)               // 100352 (mu rows 0..31, sig rows 32..63)
#define WS_TOTAL (OFF_HD + SZ_HD)             // 1171968 ushorts = 2.34 MB

__device__ __forceinline__ unsigned short f2bf(float f) {
    unsigned u = __float_as_uint(f);
    u += 0x7fffu + ((u >> 16) & 1u);          // RNE
    return (unsigned short)(u >> 16);
}

__device__ __forceinline__ float softplusf(float x) {
    float ax = fabsf(x);
    return fmaxf(x, 0.f) + log1pf(__expf(-ax));
}

// ---- prep: fp32 weights -> bf16 W^T (padded) in ws ----
__global__ void prep_kernel(const float* __restrict__ W1, const float* __restrict__ Wh,
                            const float* __restrict__ Wmu, const float* __restrict__ Wsig,
                            unsigned short* __restrict__ ws) {
    int idx = blockIdx.x * 256 + threadIdx.x;
    if (idx >= WS_TOTAL) return;
    float v = 0.f;
    if (idx < OFF_WH) {                        // layer 1: [e][n=208][k=64]
        int r = idx;
        int e = r / (NPAD * K1PAD); r %= NPAD * K1PAD;
        int n = r / K1PAD, k = r % K1PAD;
        if (n < HID && k < DIN) v = W1[(e * DIN + k) * HID + n];
    } else if (idx < OFF_HD) {                 // hidden: [l*7+e][n=208][k=224]
        int r = idx - OFF_WH;
        int le = r / (NPAD * KPAD); r %= NPAD * KPAD;
        int n = r / KPAD, k = r % KPAD;
        if (n < HID && k < HID) v = Wh[((long)le * HID + k) * HID + n];
    } else {                                   // heads: [e][n=64][k=224]
        int r = idx - OFF_HD;
        int e = r / (64 * KPAD); r %= 64 * KPAD;
        int n = r / KPAD, k = r % KPAD;
        if (k < HID) {
            if (n < DOUT) v = Wmu[(e * HID + k) * DOUT + n];
            else if (n >= 32 && n < 32 + DOUT) v = Wsig[(e * HID + k) * DOUT + (n - 32)];
        }
    }
    ws[idx] = f2bf(v);
}

// ---- fused 5-layer ensemble MLP ----
__launch_bounds__(256, 2)
__global__ void ens_mlp_kernel(const float* __restrict__ s, const float* __restrict__ a,
                               const float* __restrict__ b1, const float* __restrict__ bh,
                               const float* __restrict__ bmu, const float* __restrict__ bsig,
                               const float* __restrict__ maxs, const float* __restrict__ mins,
                               const float* __restrict__ maxr, const float* __restrict__ minr,
                               const unsigned short* __restrict__ ws,
                               float* __restrict__ out, int N) {
    __shared__ unsigned short hA[MT * HS];          // 29696 B, activations (bf16)
    __shared__ unsigned short wB[2][NPAD * WSTR];   // 33280 B, W^T K-chunk double buffer

    const int tid = threadIdx.x;
    const int wv = tid >> 6, lane = tid & 63;
    const int quad = lane >> 4, l16 = lane & 15;
    const int bid = blockIdx.x;
    const int e = bid % ENS, n0 = (bid / ENS) * MT;

    // zero hA (pad cols must be 0)
    for (int i = tid; i < MT * HS / 8; i += 256) ((uint4*)hA)[i] = make_uint4(0, 0, 0, 0);
    __syncthreads();

    // stage x = concat(s, a) -> hA cols 0..37 (bf16)
    for (int i = tid; i < MT * DIN; i += 256) {
        int m = i / DIN, c = i % DIN;
        long g = n0 + m;
        float v = (c < SDIM) ? s[(g * ENS + e) * SDIM + c]
                             : a[(g * ENS + e) * ADIM + (c - SDIM)];
        hA[m * HS + c] = f2bf(v);
    }

    f32x4 acc[4][4];   // [row-tile][col-tile j] -- ALL indices compile-time constant

    auto stageChunk = [&](const unsigned short* gW, int rstride, int nrows, int kc,
                          unsigned short* dst) {
        int items = nrows * 4;                 // 16B pieces: 32 k-elems = 4 x ushort8
        for (int i = tid; i < items; i += 256) {
            int n = i >> 2, j = i & 3;
            *((uint4*)(dst + n * WSTR + j * 8)) =
                *((const uint4*)(gW + n * rstride + kc + j * 8));
        }
    };

    // one layer: out[64][NT*16] = hA[64][K] @ W^T(rows=n), K-chunked, double-buffered.
    // col-tile ownership: wave wv owns ct = wv + 4*j, j in [0,4) fully unrolled with
    // wave-uniform guard (ct < NT) so acc[][] stays in registers (R1 lesson: runtime
    // trip count -> scratch spill -> 5 GB of HBM writes).
    auto runLayer = [&](const unsigned short* gW, int rstride, int nrows, int nsteps, int NT) {
#pragma unroll
        for (int r = 0; r < 4; r++)
#pragma unroll
            for (int j = 0; j < 4; j++) acc[r][j] = (f32x4){0.f, 0.f, 0.f, 0.f};
        stageChunk(gW, rstride, nrows, 0, wB[0]);
        __syncthreads();
        for (int st = 0; st < nsteps; ++st) {
            if (st + 1 < nsteps) stageChunk(gW, rstride, nrows, (st + 1) * 32, wB[(st + 1) & 1]);
            const unsigned short* wb = wB[st & 1];
            const int kb = st * 32;
            bf16x8 af[4];
#pragma unroll
            for (int r = 0; r < 4; r++)
                af[r] = *((const bf16x8*)(hA + (r * 16 + l16) * HS + kb + quad * 8));
#pragma unroll
            for (int j = 0; j < 4; j++) {
                int ct = wv + 4 * j;
                if (ct < NT) {
                    bf16x8 bf_ = *((const bf16x8*)(wb + (ct * 16 + l16) * WSTR + quad * 8));
#pragma unroll
                    for (int r = 0; r < 4; r++)
                        acc[r][j] = __builtin_amdgcn_mfma_f32_16x16x32_bf16(af[r], bf_, acc[r][j], 0, 0, 0);
                }
            }
            __syncthreads();
        }
    };

    // bias + swish, write back to hA as bf16
    auto epiH = [&](const float* bias, int NT) {
#pragma unroll
        for (int j = 0; j < 4; j++) {
            int ct = wv + 4 * j;
            if (ct < NT) {
                int col = ct * 16 + l16;
                float bc = (col < HID) ? bias[col] : 0.f;
#pragma unroll
                for (int r = 0; r < 4; r++)
#pragma unroll
                    for (int i = 0; i < 4; i++) {
                        float v = acc[r][j][i] + bc;
                        float sw = v / (1.f + __expf(-v));   // swish
                        hA[(r * 16 + quad * 4 + i) * HS + col] = f2bf(sw);
                    }
            }
        }
    };

    // layer 1 (K=64: 2 chunks), hidden x3 (K=224: 7 chunks), heads (NT=4)
    runLayer(ws + OFF_W1 + e * NPAD * K1PAD, K1PAD, NPAD, 2, 13);
    epiH(b1 + e * HID, 13);
    for (int l = 0; l < NHL; l++) {
        runLayer(ws + OFF_WH + (l * ENS + e) * NPAD * KPAD, KPAD, NPAD, 7, 13);
        epiH(bh + (l * ENS + e) * HID, 13);
    }
    runLayer(ws + OFF_HD + e * 64 * KPAD, KPAD, 64, 7, 4);

    // head epilogue: raw mu/sig (+bias) into fp32 scratch overlaying hA
    float* scr = (float*)hA;                   // [64][64]: cols 0..31 mu, 32..63 sig
    {
        int col = wv * 16 + l16;               // heads: wave wv owns ct = wv only (j = 0)
        float bc = 0.f;
        if (col < DOUT) bc = bmu[e * DOUT + col];
        else if (col >= 32 && col < 32 + DOUT) bc = bsig[e * DOUT + (col - 32)];
#pragma unroll
        for (int r = 0; r < 4; r++)
#pragma unroll
            for (int i = 0; i < 4; i++)
                scr[(r * 16 + quad * 4 + i) * 64 + col] = acc[r][0][i] + bc;
    }
    __syncthreads();

    const long off1 = (long)N * ENS * SDIM;    // ds_sg
    const long off2 = 2 * off1;                // r_mu
    const long off3 = off2 + (long)N * ENS;    // r_sg

    // mu outputs (no transform)
    for (int i = tid; i < MT * DOUT; i += 256) {
        int m = i / DOUT, c = i % DOUT;
        long g = n0 + m;
        float v = scr[m * 64 + c];
        if (c < SDIM) out[(g * ENS + e) * SDIM + c] = v;
        else out[off2 + g * ENS + e] = v;
    }
    // sigma outputs (clamped-softplus + exp)
    for (int i = tid; i < MT * DOUT; i += 256) {
        int m = i / DOUT, c = i % DOUT;
        long g = n0 + m;
        float v = scr[m * 64 + 32 + c];
        float mx = (c < SDIM) ? maxs[c] : maxr[0];
        float mn = (c < SDIM) ? mins[c] : minr[0];
        v = 0.5f * (mx - softplusf(mx - 2.f * v));
        v = 0.5f * (mn + softplusf(2.f * v - mn));
        v = __expf(v);
        if (c < SDIM) out[off1 + (g * ENS + e) * SDIM + c] = v;
        else out[off3 + g * ENS + e] = v;
    }
}

extern "C" void kernel_launch(void* const* d_in, const int* in_sizes, int n_in,
                              void* d_out, int out_size, void* d_ws, size_t ws_size,
                              hipStream_t stream) {
    const float* s    = (const float*)d_in[0];
    const float* a    = (const float*)d_in[1];
    const float* W1   = (const float*)d_in[2];
    const float* b1   = (const float*)d_in[3];
    const float* Wh   = (const float*)d_in[4];
    const float* bh   = (const float*)d_in[5];
    const float* Wmu  = (const float*)d_in[6];
    const float* bmu  = (const float*)d_in[7];
    const float* Wsig = (const float*)d_in[8];
    const float* bsig = (const float*)d_in[9];
    const float* maxs = (const float*)d_in[10];
    const float* mins = (const float*)d_in[11];
    const float* maxr = (const float*)d_in[12];
    const float* minr = (const float*)d_in[13];
    float* out = (float*)d_out;
    unsigned short* ws = (unsigned short*)d_ws;

    int N = in_sizes[0] / (ENS * SDIM);        // 32768

    int prepBlocks = (WS_TOTAL + 255) / 256;
    prep_kernel<<<prepBlocks, 256, 0, stream>>>(W1, Wh, Wmu, Wsig, ws);

    int mainBlocks = (N / MT) * ENS;           // 3584
    ens_mlp_kernel<<<mainBlocks, 256, 0, stream>>>(s, a, b1, bh, bmu, bsig,
                                                   maxs, mins, maxr, minr, ws, out, N);
}

// Round 3
// 434.947 us; speedup vs baseline: 3.7470x; 1.2158x over previous
//
#include <hip/hip_runtime.h>

#define ENS 7
#define SDIM 30
#define ADIM 8
#define DIN 38          // SDIM + ADIM
#define HID 200
#define DOUT 31         // SDIM + RDIM
#define NHL 3           // hidden layers
#define NPAD 208        // N (out-cols) padded to 16
#define KPAD 224        // K padded to 32
#define K1PAD 64        // layer-1 K (38) padded
#define HS 232          // hA row stride in elems (bank-safe, %8==0)
#define WSTR 32         // W-chunk row stride = K-chunk (contiguous: required by global_load_lds)
#define MT 64           // rows per block

typedef __bf16 bf16x8 __attribute__((ext_vector_type(8)));
typedef float f32x4 __attribute__((ext_vector_type(4)));

// ws layout (ushort elems): bf16 W^T, zero-padded
#define OFF_W1 0
#define SZ_W1 (ENS * NPAD * K1PAD)            // 93184
#define OFF_WH (OFF_W1 + SZ_W1)
#define SZ_WH (NHL * ENS * NPAD * KPAD)       // 978432
#define OFF_HD (OFF_WH + SZ_WH)
#define SZ_HD (ENS * 64 * KPAD)               // 100352 (mu rows 0..31, sig rows 32..63)
#define WS_TOTAL (OFF_HD + SZ_HD)             // 1171968 ushorts = 2.34 MB

__device__ __forceinline__ unsigned short f2bf(float f) {
    unsigned u = __float_as_uint(f);
    u += 0x7fffu + ((u >> 16) & 1u);          // RNE
    return (unsigned short)(u >> 16);
}

__device__ __forceinline__ float softplusf(float x) {
    float ax = fabsf(x);
    return fmaxf(x, 0.f) + log1pf(__expf(-ax));
}

// direct global->LDS DMA, 16 B per lane; LDS dest MUST be wave-uniform base + lane*16
__device__ __forceinline__ void gload_lds16(const unsigned short* src, unsigned short* dst) {
    __builtin_amdgcn_global_load_lds(
        (const __attribute__((address_space(1))) unsigned int*)src,
        (__attribute__((address_space(3))) unsigned int*)dst, 16, 0, 0);
}

// ---- prep: fp32 weights -> bf16 W^T (padded) in ws ----
__global__ void prep_kernel(const float* __restrict__ W1, const float* __restrict__ Wh,
                            const float* __restrict__ Wmu, const float* __restrict__ Wsig,
                            unsigned short* __restrict__ ws) {
    int idx = blockIdx.x * 256 + threadIdx.x;
    if (idx >= WS_TOTAL) return;
    float v = 0.f;
    if (idx < OFF_WH) {                        // layer 1: [e][n=208][k=64]
        int r = idx;
        int e = r / (NPAD * K1PAD); r %= NPAD * K1PAD;
        int n = r / K1PAD, k = r % K1PAD;
        if (n < HID && k < DIN) v = W1[(e * DIN + k) * HID + n];
    } else if (idx < OFF_HD) {                 // hidden: [l*7+e][n=208][k=224]
        int r = idx - OFF_WH;
        int le = r / (NPAD * KPAD); r %= NPAD * KPAD;
        int n = r / KPAD, k = r % KPAD;
        if (n < HID && k < HID) v = Wh[((long)le * HID + k) * HID + n];
    } else {                                   // heads: [e][n=64][k=224]
        int r = idx - OFF_HD;
        int e = r / (64 * KPAD); r %= 64 * KPAD;
        int n = r / KPAD, k = r % KPAD;
        if (k < HID) {
            if (n < DOUT) v = Wmu[(e * HID + k) * DOUT + n];
            else if (n >= 32 && n < 32 + DOUT) v = Wsig[(e * HID + k) * DOUT + (n - 32)];
        }
    }
    ws[idx] = f2bf(v);
}

// ---- fused 5-layer ensemble MLP ----
__launch_bounds__(256, 2)
__global__ void ens_mlp_kernel(const float* __restrict__ s, const float* __restrict__ a,
                               const float* __restrict__ b1, const float* __restrict__ bh,
                               const float* __restrict__ bmu, const float* __restrict__ bsig,
                               const float* __restrict__ maxs, const float* __restrict__ mins,
                               const float* __restrict__ maxr, const float* __restrict__ minr,
                               const unsigned short* __restrict__ ws,
                               float* __restrict__ out, int N) {
    __shared__ unsigned short hA[MT * HS];          // 29696 B, activations (bf16)
    __shared__ unsigned short wB[2][NPAD * WSTR];   // 26624 B, W^T K-chunk double buffer

    const int tid = threadIdx.x;
    const int wv = tid >> 6, lane = tid & 63;
    const int quad = lane >> 4, l16 = lane & 15;
    const int bid = blockIdx.x;
    const int e = bid % ENS, n0 = (bid / ENS) * MT;

    // zero hA (pad cols must be 0)
    for (int i = tid; i < MT * HS / 8; i += 256) ((uint4*)hA)[i] = make_uint4(0, 0, 0, 0);
    __syncthreads();

    // stage x = concat(s, a) -> hA cols 0..37 (bf16)
    for (int i = tid; i < MT * DIN; i += 256) {
        int m = i / DIN, c = i % DIN;
        long g = n0 + m;
        float v = (c < SDIM) ? s[(g * ENS + e) * SDIM + c]
                             : a[(g * ENS + e) * ADIM + (c - SDIM)];
        hA[m * HS + c] = f2bf(v);
    }

    f32x4 acc[4][4];   // [row-tile][col-tile j] -- ALL indices compile-time constant

    // stage one K=32 chunk of W^T rows into LDS via direct global->LDS DMA.
    // LDS layout: piece i (16 B) at dst + i*16 B -> row n = i/4 at stride 32 elems,
    // lane-linear so dest = wave-uniform base + lane*16 (HW requirement).
    auto stageChunk = [&](const unsigned short* gW, int rstride, int nrows, int kc,
                          unsigned short* dst) {
        int items = nrows * 4;                 // 16B pieces: 32 k-elems = 4 x ushort8
        for (int i = tid; i < items; i += 256) {
            int n = i >> 2, j = i & 3;
            gload_lds16(gW + n * rstride + kc + j * 8, dst + i * 8);
        }
    };

    // one layer: out[64][NT*16] = hA[64][K] @ W^T(rows=n), K-chunked, double-buffered.
    // col-tile ownership: wave wv owns ct = wv + 4*j, j in [0,4) fully unrolled with
    // wave-uniform guard (ct < NT) so acc[][] stays in registers (R1 lesson: runtime
    // trip count -> scratch spill -> 5 GB of HBM writes).
    auto runLayer = [&](const unsigned short* gW, int rstride, int nrows, int nsteps, int NT) {
#pragma unroll
        for (int r = 0; r < 4; r++)
#pragma unroll
            for (int j = 0; j < 4; j++) acc[r][j] = (f32x4){0.f, 0.f, 0.f, 0.f};
        stageChunk(gW, rstride, nrows, 0, wB[0]);
        __syncthreads();
        for (int st = 0; st < nsteps; ++st) {
            if (st + 1 < nsteps) stageChunk(gW, rstride, nrows, (st + 1) * 32, wB[(st + 1) & 1]);
            const unsigned short* wb = wB[st & 1];
            const int kb = st * 32;
            bf16x8 af[4];
#pragma unroll
            for (int r = 0; r < 4; r++)
                af[r] = *((const bf16x8*)(hA + (r * 16 + l16) * HS + kb + quad * 8));
#pragma unroll
            for (int j = 0; j < 4; j++) {
                int ct = wv + 4 * j;
                if (ct < NT) {
                    bf16x8 bf_ = *((const bf16x8*)(wb + (ct * 16 + l16) * WSTR + quad * 8));
#pragma unroll
                    for (int r = 0; r < 4; r++)
                        acc[r][j] = __builtin_amdgcn_mfma_f32_16x16x32_bf16(af[r], bf_, acc[r][j], 0, 0, 0);
                }
            }
            __syncthreads();
        }
    };

    // bias + swish, write back to hA as bf16
    auto epiH = [&](const float* bias, int NT) {
#pragma unroll
        for (int j = 0; j < 4; j++) {
            int ct = wv + 4 * j;
            if (ct < NT) {
                int col = ct * 16 + l16;
                float bc = (col < HID) ? bias[col] : 0.f;
#pragma unroll
                for (int r = 0; r < 4; r++)
#pragma unroll
                    for (int i = 0; i < 4; i++) {
                        float v = acc[r][j][i] + bc;
                        float sw = v / (1.f + __expf(-v));   // swish
                        hA[(r * 16 + quad * 4 + i) * HS + col] = f2bf(sw);
                    }
            }
        }
    };

    // layer 1 (K=64: 2 chunks), hidden x3 (K=224: 7 chunks), heads (NT=4)
    runLayer(ws + OFF_W1 + e * NPAD * K1PAD, K1PAD, NPAD, 2, 13);
    epiH(b1 + e * HID, 13);
    for (int l = 0; l < NHL; l++) {
        runLayer(ws + OFF_WH + (l * ENS + e) * NPAD * KPAD, KPAD, NPAD, 7, 13);
        epiH(bh + (l * ENS + e) * HID, 13);
    }
    runLayer(ws + OFF_HD + e * 64 * KPAD, KPAD, 64, 7, 4);

    // head epilogue: raw mu/sig (+bias) into fp32 scratch overlaying hA
    float* scr = (float*)hA;                   // [64][64]: cols 0..31 mu, 32..63 sig
    {
        int col = wv * 16 + l16;               // heads: wave wv owns ct = wv only (j = 0)
        float bc = 0.f;
        if (col < DOUT) bc = bmu[e * DOUT + col];
        else if (col >= 32 && col < 32 + DOUT) bc = bsig[e * DOUT + (col - 32)];
#pragma unroll
        for (int r = 0; r < 4; r++)
#pragma unroll
            for (int i = 0; i < 4; i++)
                scr[(r * 16 + quad * 4 + i) * 64 + col] = acc[r][0][i] + bc;
    }
    __syncthreads();

    const long off1 = (long)N * ENS * SDIM;    // ds_sg
    const long off2 = 2 * off1;                // r_mu
    const long off3 = off2 + (long)N * ENS;    // r_sg

    // mu outputs (no transform)
    for (int i = tid; i < MT * DOUT; i += 256) {
        int m = i / DOUT, c = i % DOUT;
        long g = n0 + m;
        float v = scr[m * 64 + c];
        if (c < SDIM) out[(g * ENS + e) * SDIM + c] = v;
        else out[off2 + g * ENS + e] = v;
    }
    // sigma outputs (clamped-softplus + exp)
    for (int i = tid; i < MT * DOUT; i += 256) {
        int m = i / DOUT, c = i % DOUT;
        long g = n0 + m;
        float v = scr[m * 64 + 32 + c];
        float mx = (c < SDIM) ? maxs[c] : maxr[0];
        float mn = (c < SDIM) ? mins[c] : minr[0];
        v = 0.5f * (mx - softplusf(mx - 2.f * v));
        v = 0.5f * (mn + softplusf(2.f * v - mn));
        v = __expf(v);
        if (c < SDIM) out[off1 + (g * ENS + e) * SDIM + c] = v;
        else out[off3 + g * ENS + e] = v;
    }
}

extern "C" void kernel_launch(void* const* d_in, const int* in_sizes, int n_in,
                              void* d_out, int out_size, void* d_ws, size_t ws_size,
                              hipStream_t stream) {
    const float* s    = (const float*)d_in[0];
    const float* a    = (const float*)d_in[1];
    const float* W1   = (const float*)d_in[2];
    const float* b1   = (const float*)d_in[3];
    const float* Wh   = (const float*)d_in[4];
    const float* bh   = (const float*)d_in[5];
    const float* Wmu  = (const float*)d_in[6];
    const float* bmu  = (const float*)d_in[7];
    const float* Wsig = (const float*)d_in[8];
    const float* bsig = (const float*)d_in[9];
    const float* maxs = (const float*)d_in[10];
    const float* mins = (const float*)d_in[11];
    const float* maxr = (const float*)d_in[12];
    const float* minr = (const float*)d_in[13];
    float* out = (float*)d_out;
    unsigned short* ws = (unsigned short*)d_ws;

    int N = in_sizes[0] / (ENS * SDIM);        // 32768

    int prepBlocks = (WS_TOTAL + 255) / 256;
    prep_kernel<<<prepBlocks, 256, 0, stream>>>(W1, Wh, Wmu, Wsig, ws);

    int mainBlocks = (N / MT) * ENS;           // 3584
    ens_mlp_kernel<<<mainBlocks, 256, 0, stream>>>(s, a, b1, bh, bmu, bsig,
                                                   maxs, mins, maxr, minr, ws, out, N);
}

// Round 4
// 272.626 us; speedup vs baseline: 5.9780x; 1.5954x over previous
//
#include <hip/hip_runtime.h>

#define ENS 7
#define SDIM 30
#define ADIM 8
#define DIN 38          // SDIM + ADIM
#define HID 200
#define DOUT 31         // SDIM + RDIM
#define NHL 3           // hidden layers
#define HS 232          // hA row stride in elems (bank-safe: 116 words -> <=2-way on b128)
#define MT 64           // rows per block

typedef __bf16 bf16x8 __attribute__((ext_vector_type(8)));
typedef float f32x4 __attribute__((ext_vector_type(4)));

// ws layout (ushort elems): bf16 weights pre-swizzled into MFMA B-fragment order.
// Per ensemble e, per layer-unit: fragment (ct,st) is a contiguous 512-ushort (1024 B)
// block at (ct*S + st)*512; element (lane, j) = W[k = st*32 + (lane>>4)*8 + j]
//                                               [n = ct*16 + (lane&15)]  (0 if OOB)
// Units per e: L1 (S=2,NT=13) 13312 | H0..H2 (S=7,NT=13) 46592 each | HD (S=7,NT=4) 14336
#define U_L1 13312
#define U_H 46592
#define OFF_HD2 (U_L1 + NHL * U_H)            // 153088
#define PER_E (OFF_HD2 + 14336)               // 167424
#define WS_TOTAL (ENS * PER_E)                // 1171968 ushorts = 2.34 MB

__device__ __forceinline__ unsigned short f2bf(float f) {
    unsigned u = __float_as_uint(f);
    u += 0x7fffu + ((u >> 16) & 1u);          // RNE
    return (unsigned short)(u >> 16);
}

// cheap softplus: max(x,0) + log(1+exp(-|x|)); hw log/exp approx, abs err ~1e-7
__device__ __forceinline__ float softplusf(float x) {
    return fmaxf(x, 0.f) + __logf(1.f + __expf(-fabsf(x)));
}

// ---- prep: fp32 weights -> bf16 fragment-order in ws ----
__global__ void prep_kernel(const float* __restrict__ W1, const float* __restrict__ Wh,
                            const float* __restrict__ Wmu, const float* __restrict__ Wsig,
                            unsigned short* __restrict__ ws) {
    int idx = blockIdx.x * 256 + threadIdx.x;
    if (idx >= WS_TOTAL) return;
    int e = idx / PER_E, r = idx % PER_E;
    int j = r & 7, lane = (r >> 3) & 63;
    int l16 = lane & 15, q = lane >> 4;
    float v = 0.f;
    if (r < U_L1) {                            // layer 1
        int fi = r >> 9;                       // ct*2 + st
        int ct = fi >> 1, st = fi & 1;
        int k = st * 32 + q * 8 + j, n = ct * 16 + l16;
        if (k < DIN && n < HID) v = W1[(e * DIN + k) * HID + n];
    } else if (r < OFF_HD2) {                  // hidden layers
        int rh = r - U_L1;
        int l = rh / U_H, r2 = rh % U_H;
        int fi = r2 >> 9;                      // ct*7 + st
        int ct = fi / 7, st = fi % 7;
        int k = st * 32 + q * 8 + j, n = ct * 16 + l16;
        if (k < HID && n < HID) v = Wh[((l * ENS + e) * HID + (long)k) * HID + n];
    } else {                                   // heads (mu cols 0..30, sig cols 32..62)
        int r2 = r - OFF_HD2;
        int fi = r2 >> 9;
        int ct = fi / 7, st = fi % 7;
        int k = st * 32 + q * 8 + j, n = ct * 16 + l16;
        if (k < HID) {
            if (n < DOUT) v = Wmu[(e * HID + k) * DOUT + n];
            else if (n >= 32 && n < 32 + DOUT) v = Wsig[(e * HID + k) * DOUT + (n - 32)];
        }
    }
    ws[idx] = f2bf(v);
}

// one layer: acc[64][NT*16] = hA[64][S*32] @ W; B-fragments straight from global
// (pre-swizzled, coalesced dwordx4, L2-resident), A-fragments from LDS.
// No barriers inside -- global loads pipeline with fine-grained vmcnt.
template<int S, int NT>
__device__ __forceinline__ void runLayer(const unsigned short* __restrict__ gB,
                                         const unsigned short* hA,
                                         int wv, int l16, int quad,
                                         f32x4 acc[4][4]) {
#pragma unroll
    for (int r = 0; r < 4; r++)
#pragma unroll
        for (int j = 0; j < 4; j++) acc[r][j] = (f32x4){0.f, 0.f, 0.f, 0.f};

    const unsigned short* fp = gB + (quad * 16 + l16) * 8;   // + lane*16 B
    bf16x8 bcur[4], bnxt[4];
#pragma unroll
    for (int j = 0; j < 4; j++) {
        int ct = wv + 4 * j;
        if (ct < NT) bcur[j] = *((const bf16x8*)(fp + (ct * S) * 512));
    }
#pragma unroll
    for (int st = 0; st < S; ++st) {
        if (st + 1 < S) {
#pragma unroll
            for (int j = 0; j < 4; j++) {
                int ct = wv + 4 * j;
                if (ct < NT) bnxt[j] = *((const bf16x8*)(fp + (ct * S + st + 1) * 512));
            }
        }
        bf16x8 af[4];
#pragma unroll
        for (int r = 0; r < 4; r++)
            af[r] = *((const bf16x8*)(hA + (r * 16 + l16) * HS + st * 32 + quad * 8));
#pragma unroll
        for (int j = 0; j < 4; j++) {
            int ct = wv + 4 * j;
            if (ct < NT) {
#pragma unroll
                for (int r = 0; r < 4; r++)
                    acc[r][j] = __builtin_amdgcn_mfma_f32_16x16x32_bf16(af[r], bcur[j], acc[r][j], 0, 0, 0);
            }
        }
#pragma unroll
        for (int j = 0; j < 4; j++) bcur[j] = bnxt[j];
    }
}

// ---- fused 5-layer ensemble MLP ----
__launch_bounds__(256, 3)
__global__ void ens_mlp_kernel(const float* __restrict__ s, const float* __restrict__ a,
                               const float* __restrict__ b1, const float* __restrict__ bh,
                               const float* __restrict__ bmu, const float* __restrict__ bsig,
                               const float* __restrict__ maxs, const float* __restrict__ mins,
                               const float* __restrict__ maxr, const float* __restrict__ minr,
                               const unsigned short* __restrict__ ws,
                               float* __restrict__ out, int N) {
    __shared__ unsigned short hA[MT * HS];     // 29696 B, activations (bf16) -- only LDS

    const int tid = threadIdx.x;
    const int wv = tid >> 6, lane = tid & 63;
    const int quad = lane >> 4, l16 = lane & 15;
    const int bid = blockIdx.x;
    const int e = bid % ENS, n0 = (bid / ENS) * MT;

    // zero hA (pad cols must be 0)
    for (int i = tid; i < MT * HS / 8; i += 256) ((uint4*)hA)[i] = make_uint4(0, 0, 0, 0);
    __syncthreads();

    // stage x = concat(s, a) -> hA cols 0..37 (bf16)
    for (int i = tid; i < MT * DIN; i += 256) {
        int m = i / DIN, c = i % DIN;
        long g = n0 + m;
        float v = (c < SDIM) ? s[(g * ENS + e) * SDIM + c]
                             : a[(g * ENS + e) * ADIM + (c - SDIM)];
        hA[m * HS + c] = f2bf(v);
    }
    __syncthreads();

    f32x4 acc[4][4];   // [row-tile][col-tile j] -- ALL indices compile-time constant

    // bias + swish, write back to hA as bf16 (rcp-based sigmoid: bf16-accurate)
    auto epiH = [&](const float* bias) {
#pragma unroll
        for (int j = 0; j < 4; j++) {
            int ct = wv + 4 * j;
            if (ct < 13) {
                int col = ct * 16 + l16;
                float bc = (col < HID) ? bias[col] : 0.f;
#pragma unroll
                for (int r = 0; r < 4; r++)
#pragma unroll
                    for (int i = 0; i < 4; i++) {
                        float v = acc[r][j][i] + bc;
                        float sw = v * __builtin_amdgcn_rcpf(1.f + __expf(-v));
                        hA[(r * 16 + quad * 4 + i) * HS + col] = f2bf(sw);
                    }
            }
        }
    };

    const unsigned short* we = ws + e * PER_E;

    runLayer<2, 13>(we, hA, wv, l16, quad, acc);
    __syncthreads();
    epiH(b1 + e * HID);
    __syncthreads();
#pragma unroll
    for (int l = 0; l < NHL; l++) {
        runLayer<7, 13>(we + U_L1 + l * U_H, hA, wv, l16, quad, acc);
        __syncthreads();
        epiH(bh + (l * ENS + e) * HID);
        __syncthreads();
    }
    runLayer<7, 4>(we + OFF_HD2, hA, wv, l16, quad, acc);
    __syncthreads();

    // head epilogue: raw mu/sig (+bias) into fp32 scratch overlaying hA
    float* scr = (float*)hA;                   // [64][64]: cols 0..31 mu, 32..63 sig
    {
        int col = wv * 16 + l16;               // heads: wave wv owns ct = wv only (j = 0)
        float bc = 0.f;
        if (col < DOUT) bc = bmu[e * DOUT + col];
        else if (col >= 32 && col < 32 + DOUT) bc = bsig[e * DOUT + (col - 32)];
#pragma unroll
        for (int r = 0; r < 4; r++)
#pragma unroll
            for (int i = 0; i < 4; i++)
                scr[(r * 16 + quad * 4 + i) * 64 + col] = acc[r][0][i] + bc;
    }
    __syncthreads();

    const long off1 = (long)N * ENS * SDIM;    // ds_sg
    const long off2 = 2 * off1;                // r_mu
    const long off3 = off2 + (long)N * ENS;    // r_sg

    // mu outputs (no transform)
    for (int i = tid; i < MT * DOUT; i += 256) {
        int m = i / DOUT, c = i % DOUT;
        long g = n0 + m;
        float v = scr[m * 64 + c];
        if (c < SDIM) out[(g * ENS + e) * SDIM + c] = v;
        else out[off2 + g * ENS + e] = v;
    }
    // sigma outputs (clamped-softplus + exp)
    for (int i = tid; i < MT * DOUT; i += 256) {
        int m = i / DOUT, c = i % DOUT;
        long g = n0 + m;
        float v = scr[m * 64 + 32 + c];
        float mx = (c < SDIM) ? maxs[c] : maxr[0];
        float mn = (c < SDIM) ? mins[c] : minr[0];
        v = 0.5f * (mx - softplusf(mx - 2.f * v));
        v = 0.5f * (mn + softplusf(2.f * v - mn));
        v = __expf(v);
        if (c < SDIM) out[off1 + (g * ENS + e) * SDIM + c] = v;
        else out[off3 + g * ENS + e] = v;
    }
}

extern "C" void kernel_launch(void* const* d_in, const int* in_sizes, int n_in,
                              void* d_out, int out_size, void* d_ws, size_t ws_size,
                              hipStream_t stream) {
    const float* s    = (const float*)d_in[0];
    const float* a    = (const float*)d_in[1];
    const float* W1   = (const float*)d_in[2];
    const float* b1   = (const float*)d_in[3];
    const float* Wh   = (const float*)d_in[4];
    const float* bh   = (const float*)d_in[5];
    const float* Wmu  = (const float*)d_in[6];
    const float* bmu  = (const float*)d_in[7];
    const float* Wsig = (const float*)d_in[8];
    const float* bsig = (const float*)d_in[9];
    const float* maxs = (const float*)d_in[10];
    const float* mins = (const float*)d_in[11];
    const float* maxr = (const float*)d_in[12];
    const float* minr = (const float*)d_in[13];
    float* out = (float*)d_out;
    unsigned short* ws = (unsigned short*)d_ws;

    int N = in_sizes[0] / (ENS * SDIM);        // 32768

    int prepBlocks = (WS_TOTAL + 255) / 256;
    prep_kernel<<<prepBlocks, 256, 0, stream>>>(W1, Wh, Wmu, Wsig, ws);

    int mainBlocks = (N / MT) * ENS;           // 3584
    ens_mlp_kernel<<<mainBlocks, 256, 0, stream>>>(s, a, b1, bh, bmu, bsig,
                                                   maxs, mins, maxr, minr, ws, out, N);
}

// Round 5
// 264.319 us; speedup vs baseline: 6.1658x; 1.0314x over previous
//
#include <hip/hip_runtime.h>
#include <hip/hip_bf16.h>

#define ENS 7
#define SDIM 30
#define ADIM 8
#define DIN 38          // SDIM + ADIM
#define HID 200
#define DOUT 31         // SDIM + RDIM
#define NHL 3           // hidden layers
#define HS 232          // hA row stride in elems (row = 464 B: 8B-aligned, b128/b64 reads 2-way max)
#define MT 64           // rows per block

typedef __bf16 bf16x8 __attribute__((ext_vector_type(8)));
typedef float f32x4 __attribute__((ext_vector_type(4)));

// ws layout (ushort elems): bf16 weights pre-swizzled into MFMA fragment order.
// Fragment (ct,st) = contiguous 512-ushort (1024 B) block at (ct*S + st)*512;
// element (lane, j) = W[k = st*32 + (lane>>4)*8 + j][n = ct*16 + (lane&15)]  (0 if OOB)
// Used as the MFMA *A* operand (m = out-col = lane&15) -- same layout either way.
// Units per e: L1 (S=2,NT=13) 13312 | H0..H2 (S=7,NT=13) 46592 each | HD (S=7,NT=4) 14336
#define U_L1 13312
#define U_H 46592
#define OFF_HD2 (U_L1 + NHL * U_H)            // 153088
#define PER_E (OFF_HD2 + 14336)               // 167424
#define WS_TOTAL (ENS * PER_E)                // 1171968 ushorts = 2.34 MB

__device__ __forceinline__ unsigned short f2bf(float f) {
    unsigned u = __float_as_uint(f);
    u += 0x7fffu + ((u >> 16) & 1u);          // RNE
    return (unsigned short)(u >> 16);
}

// pack 2 floats -> 2 bf16 in one reg (v_cvt_pk_bf16_f32 on gfx950)
__device__ __forceinline__ unsigned pk2(float a, float b) {
    __hip_bfloat162 h = __float22bfloat162_rn(make_float2(a, b));
    return *reinterpret_cast<unsigned*>(&h);
}

// cheap softplus: max(x,0) + log(1+exp(-|x|)); hw log/exp approx, abs err ~1e-7
__device__ __forceinline__ float softplusf(float x) {
    return fmaxf(x, 0.f) + __logf(1.f + __expf(-fabsf(x)));
}

// ---- prep: fp32 weights -> bf16 fragment-order in ws (unchanged from R4) ----
__global__ void prep_kernel(const float* __restrict__ W1, const float* __restrict__ Wh,
                            const float* __restrict__ Wmu, const float* __restrict__ Wsig,
                            unsigned short* __restrict__ ws) {
    int idx = blockIdx.x * 256 + threadIdx.x;
    if (idx >= WS_TOTAL) return;
    int e = idx / PER_E, r = idx % PER_E;
    int j = r & 7, lane = (r >> 3) & 63;
    int l16 = lane & 15, q = lane >> 4;
    float v = 0.f;
    if (r < U_L1) {                            // layer 1
        int fi = r >> 9;                       // ct*2 + st
        int ct = fi >> 1, st = fi & 1;
        int k = st * 32 + q * 8 + j, n = ct * 16 + l16;
        if (k < DIN && n < HID) v = W1[(e * DIN + k) * HID + n];
    } else if (r < OFF_HD2) {                  // hidden layers
        int rh = r - U_L1;
        int l = rh / U_H, r2 = rh % U_H;
        int fi = r2 >> 9;                      // ct*7 + st
        int ct = fi / 7, st = fi % 7;
        int k = st * 32 + q * 8 + j, n = ct * 16 + l16;
        if (k < HID && n < HID) v = Wh[((l * ENS + e) * HID + (long)k) * HID + n];
    } else {                                   // heads (mu cols 0..30, sig cols 32..62)
        int r2 = r - OFF_HD2;
        int fi = r2 >> 9;
        int ct = fi / 7, st = fi % 7;
        int k = st * 32 + q * 8 + j, n = ct * 16 + l16;
        if (k < HID) {
            if (n < DOUT) v = Wmu[(e * HID + k) * DOUT + n];
            else if (n >= 32 && n < 32 + DOUT) v = Wsig[(e * HID + k) * DOUT + (n - 32)];
        }
    }
    ws[idx] = f2bf(v);
}

// one layer: acc = W(frag, A-operand) x act(frag from LDS, B-operand).
// OPERANDS SWAPPED vs R4: D[m = out-col][n = batch-row], so each lane holds
// 4 CONSECUTIVE OUT-COLS (quad*4+i) of batch row (rt*16 + l16) -> packable epilogue.
template<int S, int NT>
__device__ __forceinline__ void runLayer(const unsigned short* __restrict__ gB,
                                         const unsigned short* hA,
                                         int wv, int lane, int l16, int quad,
                                         f32x4 acc[4][4]) {
#pragma unroll
    for (int r = 0; r < 4; r++)
#pragma unroll
        for (int j = 0; j < 4; j++) acc[r][j] = (f32x4){0.f, 0.f, 0.f, 0.f};

    const unsigned short* fp = gB + lane * 8;   // + lane*16 B within each fragment
    bf16x8 bcur[4], bnxt[4];
#pragma unroll
    for (int j = 0; j < 4; j++) {
        int ct = wv + 4 * j;
        if (ct < NT) bcur[j] = *((const bf16x8*)(fp + (ct * S) * 512));
    }
#pragma unroll
    for (int st = 0; st < S; ++st) {
        if (st + 1 < S) {
#pragma unroll
            for (int j = 0; j < 4; j++) {
                int ct = wv + 4 * j;
                if (ct < NT) bnxt[j] = *((const bf16x8*)(fp + (ct * S + st + 1) * 512));
            }
        }
        bf16x8 af[4];
#pragma unroll
        for (int r = 0; r < 4; r++)
            af[r] = *((const bf16x8*)(hA + (r * 16 + l16) * HS + st * 32 + quad * 8));
#pragma unroll
        for (int j = 0; j < 4; j++) {
            int ct = wv + 4 * j;
            if (ct < NT) {
#pragma unroll
                for (int r = 0; r < 4; r++)   // SWAPPED: weights=A, activations=B
                    acc[r][j] = __builtin_amdgcn_mfma_f32_16x16x32_bf16(bcur[j], af[r], acc[r][j], 0, 0, 0);
            }
        }
#pragma unroll
        for (int j = 0; j < 4; j++) bcur[j] = bnxt[j];
    }
}

// ---- fused 5-layer ensemble MLP ----
__launch_bounds__(256, 3)
__global__ void ens_mlp_kernel(const float* __restrict__ s, const float* __restrict__ a,
                               const float* __restrict__ b1, const float* __restrict__ bh,
                               const float* __restrict__ bmu, const float* __restrict__ bsig,
                               const float* __restrict__ maxs, const float* __restrict__ mins,
                               const float* __restrict__ maxr, const float* __restrict__ minr,
                               const unsigned short* __restrict__ ws,
                               float* __restrict__ out, int N) {
    __shared__ unsigned short hA[MT * HS];     // 29696 B, activations (bf16) -- only LDS

    const int tid = threadIdx.x;
    const int wv = tid >> 6, lane = tid & 63;
    const int quad = lane >> 4, l16 = lane & 15;
    const int bid = blockIdx.x;
    const int e = bid % ENS, n0 = (bid / ENS) * MT;

    // zero hA (pad cols must be 0)
    for (int i = tid; i < MT * HS / 8; i += 256) ((uint4*)hA)[i] = make_uint4(0, 0, 0, 0);
    __syncthreads();

    // stage x = concat(s, a) -> hA cols 0..37 (bf16); shift/mask indexing, no div
    {
        int m = tid & 63, cg = tid >> 6;
        long g = n0 + m;
        const float* srow = s + (g * ENS + e) * SDIM;
        const float* arow = a + (g * ENS + e) * ADIM;
#pragma unroll
        for (int k = 0; k < 10; k++) {
            int c = cg * 10 + k;
            if (c < DIN) {
                float v = (c < SDIM) ? srow[c] : arow[c - SDIM];
                hA[m * HS + c] = f2bf(v);
            }
        }
    }
    __syncthreads();

    f32x4 acc[4][4];   // [row-tile][col-tile j] -- ALL indices compile-time constant

    // bias + swish, write back to hA: 4 consecutive cols per lane -> 1 ds_write_b64
    auto epiH = [&](const float* bias) {
#pragma unroll
        for (int j = 0; j < 4; j++) {
            int ct = wv + 4 * j;
            if (ct < 13) {
                int col = ct * 16 + quad * 4;
                float4 bc4 = make_float4(0.f, 0.f, 0.f, 0.f);
                if (col < HID) bc4 = *((const float4*)(bias + col));   // col=196 grp ends at 199
#pragma unroll
                for (int r = 0; r < 4; r++) {
                    int row = r * 16 + l16;
                    float v0 = acc[r][j][0] + bc4.x, v1 = acc[r][j][1] + bc4.y;
                    float v2 = acc[r][j][2] + bc4.z, v3 = acc[r][j][3] + bc4.w;
                    v0 *= __builtin_amdgcn_rcpf(1.f + __expf(-v0));
                    v1 *= __builtin_amdgcn_rcpf(1.f + __expf(-v1));
                    v2 *= __builtin_amdgcn_rcpf(1.f + __expf(-v2));
                    v3 *= __builtin_amdgcn_rcpf(1.f + __expf(-v3));
                    *((uint2*)(hA + row * HS + col)) = make_uint2(pk2(v0, v1), pk2(v2, v3));
                }
            }
        }
    };

    const unsigned short* we = ws + e * PER_E;

    runLayer<2, 13>(we, hA, wv, lane, l16, quad, acc);
    __syncthreads();
    epiH(b1 + e * HID);
    __syncthreads();
#pragma unroll
    for (int l = 0; l < NHL; l++) {
        runLayer<7, 13>(we + U_L1 + l * U_H, hA, wv, lane, l16, quad, acc);
        __syncthreads();
        epiH(bh + (l * ENS + e) * HID);
        __syncthreads();
    }
    runLayer<7, 4>(we + OFF_HD2, hA, wv, lane, l16, quad, acc);
    // no barrier: head tail reads only registers, writes only global

    // head tail: lane holds cols wv*16+quad*4+{0..3} (mu block 0..31 for wv<2,
    // sigma block 32..63 for wv>=2), rows r*16+l16. Direct global stores.
    const long off1 = (long)N * ENS * SDIM;    // ds_sg
    const long off2 = 2 * off1;                // r_mu
    const long off3 = off2 + (long)N * ENS;    // r_sg
    {
        const bool isSig = (wv >= 2);
        const int c0 = (wv & 1) * 16 + quad * 4;   // local col in its 32-block
        float bias_i[4], mx_i[4], mn_i[4];
#pragma unroll
        for (int i = 0; i < 4; i++) {
            int c = c0 + i;
            bias_i[i] = (c < DOUT) ? (isSig ? bsig : bmu)[e * DOUT + c] : 0.f;
            if (isSig) {
                mx_i[i] = (c < SDIM) ? maxs[c] : maxr[0];
                mn_i[i] = (c < SDIM) ? mins[c] : minr[0];
            }
        }
#pragma unroll
        for (int r = 0; r < 4; r++) {
            long g = n0 + r * 16 + l16;
            long rowbase = (g * ENS + e) * SDIM;
#pragma unroll
            for (int i = 0; i < 4; i++) {
                int c = c0 + i;
                if (c < DOUT) {
                    float v = acc[r][0][i] + bias_i[i];
                    if (!isSig) {
                        if (c < SDIM) out[rowbase + c] = v;
                        else out[off2 + g * ENS + e] = v;
                    } else {
                        v = 0.5f * (mx_i[i] - softplusf(mx_i[i] - 2.f * v));
                        v = 0.5f * (mn_i[i] + softplusf(2.f * v - mn_i[i]));
                        v = __expf(v);
                        if (c < SDIM) out[off1 + rowbase + c] = v;
                        else out[off3 + g * ENS + e] = v;
                    }
                }
            }
        }
    }
}

extern "C" void kernel_launch(void* const* d_in, const int* in_sizes, int n_in,
                              void* d_out, int out_size, void* d_ws, size_t ws_size,
                              hipStream_t stream) {
    const float* s    = (const float*)d_in[0];
    const float* a    = (const float*)d_in[1];
    const float* W1   = (const float*)d_in[2];
    const float* b1   = (const float*)d_in[3];
    const float* Wh   = (const float*)d_in[4];
    const float* bh   = (const float*)d_in[5];
    const float* Wmu  = (const float*)d_in[6];
    const float* bmu  = (const float*)d_in[7];
    const float* Wsig = (const float*)d_in[8];
    const float* bsig = (const float*)d_in[9];
    const float* maxs = (const float*)d_in[10];
    const float* mins = (const float*)d_in[11];
    const float* maxr = (const float*)d_in[12];
    const float* minr = (const float*)d_in[13];
    float* out = (float*)d_out;
    unsigned short* ws = (unsigned short*)d_ws;

    int N = in_sizes[0] / (ENS * SDIM);        // 32768

    int prepBlocks = (WS_TOTAL + 255) / 256;
    prep_kernel<<<prepBlocks, 256, 0, stream>>>(W1, Wh, Wmu, Wsig, ws);

    int mainBlocks = (N / MT) * ENS;           // 3584
    ens_mlp_kernel<<<mainBlocks, 256, 0, stream>>>(s, a, b1, bh, bmu, bsig,
                                                   maxs, mins, maxr, minr, ws, out, N);
}